// Round 7
// baseline (36.753 us; speedup 1.0000x reference)
//
#include <hip/hip_runtime.h>

#define BLOCK 256
#define EMBED 128
#define VOCAB 50257

// Wave-per-token, quad-per-depth. No LDS staging, no barriers in the hot
// path: one 64-lane wave owns token t; quad q (lanes 4q..4q+3) handles
// depths q and q+16 (loop covers D>32). Lane reads float4 k*4+sub of both
// the emb row (same addr across quads -> TA-merged to 1 line/instr) and its
// quad's fc rows (4 lanes cover a whole 64B line). Padded path entries are
// {idx=0, code=0, mask=0} in the input, so everything is branchless,
// weighted by mask; invalid quads read row 0 (TA-merged, L1-hot).
__global__ __launch_bounds__(BLOCK) void hs_main(
    const float* __restrict__ emb,        // [T, 128]
    const int*   __restrict__ target,     // [T]
    const float* __restrict__ fc,         // [V-1, 128]
    const int*   __restrict__ path_idx,   // [V, D]
    const float* __restrict__ path_code,  // [V, D]
    const float* __restrict__ path_mask,  // [V, D]
    int T, int D,
    float* __restrict__ partial_b,        // [gridDim.x]
    float* __restrict__ partial_c)        // [gridDim.x]
{
    __shared__ float sb[BLOCK / 64];
    __shared__ float sc[BLOCK / 64];

    const int lane = threadIdx.x & 63;
    const int q    = lane >> 2;                       // quad id 0..15
    const int sub  = lane & 3;                        // sub-lane in quad
    const int wid  = blockIdx.x * (BLOCK / 64) + (threadIdx.x >> 6);
    const int nw   = gridDim.x * (BLOCK / 64);

    float accb = 0.f, accc = 0.f;

    for (int t = wid; t < T; t += nw) {
        const int v = target[t];                      // wave-uniform

        // emb row: lane's 8 float4s (k*4+sub); identical across quads.
        const float4* e4 = (const float4*)(emb + (size_t)t * EMBED);
        float4 ev[8];
        #pragma unroll
        for (int k = 0; k < 8; ++k) ev[k] = e4[k * 4 + sub];

        const int*   ip = path_idx  + (size_t)v * D;
        const float* cp = path_code + (size_t)v * D;
        const float* mp = path_mask + (size_t)v * D;

        for (int d0 = q; d0 < D; d0 += 32) {
            const int dB = d0 + 16;
            const float mA = mp[d0];                  // 1 line per wave-instr
            const int   rA = ip[d0];
            const float cA = cp[d0];
            float mB = 0.f; int rB = 0; float cB = 0.f;
            if (dB < D) { mB = mp[dB]; rB = ip[dB]; cB = cp[dB]; }

            const float4* wA4 = (const float4*)(fc + (size_t)rA * EMBED);
            const float4* wB4 = (const float4*)(fc + (size_t)rB * EMBED);

            float a0 = 0.f, a1 = 0.f, b0 = 0.f, b1 = 0.f;
            #pragma unroll
            for (int k = 0; k < 8; ++k) {
                const float4 wa = wA4[k * 4 + sub];
                const float4 wb = wB4[k * 4 + sub];
                a0 = fmaf(ev[k].x, wa.x, a0); a1 = fmaf(ev[k].y, wa.y, a1);
                a0 = fmaf(ev[k].z, wa.z, a0); a1 = fmaf(ev[k].w, wa.w, a1);
                b0 = fmaf(ev[k].x, wb.x, b0); b1 = fmaf(ev[k].y, wb.y, b1);
                b0 = fmaf(ev[k].z, wb.z, b0); b1 = fmaf(ev[k].w, wb.w, b1);
            }
            float xA = a0 + a1, xB = b0 + b1;
            xA += __shfl_xor(xA, 1);  xA += __shfl_xor(xA, 2);
            xB += __shfl_xor(xB, 1);  xB += __shfl_xor(xB, 2);

            accb += mA * (fmaxf(xA, 0.f) - xA * cA
                          + __logf(1.f + __expf(-fabsf(xA))));
            accb += mB * (fmaxf(xB, 0.f) - xB * cB
                          + __logf(1.f + __expf(-fabsf(xB))));
            accc += mA + mB;                  // 4x quad overcount cancels
        }
    }

    // Wave reduce, then block reduce (the only barrier in the kernel).
    #pragma unroll
    for (int o = 32; o > 0; o >>= 1) {
        accb += __shfl_xor(accb, o);
        accc += __shfl_xor(accc, o);
    }
    const int wave = threadIdx.x >> 6;
    if (lane == 0) { sb[wave] = accb; sc[wave] = accc; }
    __syncthreads();
    if (threadIdx.x == 0) {
        float b = 0.f, c = 0.f;
        #pragma unroll
        for (int i = 0; i < BLOCK / 64; ++i) { b += sb[i]; c += sc[i]; }
        partial_b[blockIdx.x] = b;
        partial_c[blockIdx.x] = c;
    }
}

// Deterministic single-block finalize: double-precision sums, then divide.
__global__ __launch_bounds__(256) void hs_finalize(
    const float* __restrict__ pb,
    const float* __restrict__ pc,
    int n, float* __restrict__ out)
{
    __shared__ double rb[256];
    __shared__ double rc[256];

    double sbv = 0.0, scv = 0.0;
    for (int i = threadIdx.x; i < n; i += 256) {
        sbv += (double)pb[i];
        scv += (double)pc[i];
    }
    rb[threadIdx.x] = sbv;
    rc[threadIdx.x] = scv;
    __syncthreads();

    for (int s = 128; s > 0; s >>= 1) {
        if (threadIdx.x < s) {
            rb[threadIdx.x] += rb[threadIdx.x + s];
            rc[threadIdx.x] += rc[threadIdx.x + s];
        }
        __syncthreads();
    }
    if (threadIdx.x == 0) out[0] = (float)(rb[0] / rc[0]);
}

extern "C" void kernel_launch(void* const* d_in, const int* in_sizes, int n_in,
                              void* d_out, int out_size, void* d_ws, size_t ws_size,
                              hipStream_t stream) {
    const float* emb   = (const float*)d_in[0];
    const int*   tgt   = (const int*)  d_in[1];
    const float* fc    = (const float*)d_in[2];
    const int*   pidx  = (const int*)  d_in[3];
    const float* pcode = (const float*)d_in[4];
    const float* pmask = (const float*)d_in[5];

    const int T = in_sizes[1];            // 32768 tokens
    const int D = in_sizes[3] / VOCAB;    // padded max path depth

    const int nblocks = 2048;             // 8192 waves -> 4 tokens/wave

    float* pb = (float*)d_ws;
    float* pc = pb + nblocks;
    float* out = (float*)d_out;

    hs_main<<<nblocks, BLOCK, 0, stream>>>(
        emb, tgt, fc, pidx, pcode, pmask, T, D, pb, pc);
    hs_finalize<<<1, 256, 0, stream>>>(pb, pc, nblocks, out);
}

// Round 8
// 34.437 us; speedup vs baseline: 1.0673x; 1.0673x over previous
//
#include <hip/hip_runtime.h>

#define TILE    64
#define BLOCK   512
#define EMBED   128
#define VOCAB   50257
#define ESTRIDE 132   // 4*odd floats: spreads rows across bank-groups

// R5 structure (quad-per-item, LDS-staged emb + path meta, d-major items)
// with a 4x larger token tile: 64 tokens/block so the shared top-of-tree fc
// rows are fetched once per block instead of 4x (per-CU L1-miss line traffic
// is the measured floor). 8 waves/block, 512 blocks, ~47KB LDS -> 3 blk/CU.
__global__ __launch_bounds__(BLOCK) void hs_main(
    const float* __restrict__ emb,        // [T, 128]
    const int*   __restrict__ target,     // [T]
    const float* __restrict__ fc,         // [V-1, 128]
    const int*   __restrict__ path_idx,   // [V, D]
    const float* __restrict__ path_code,  // [V, D]
    const float* __restrict__ path_mask,  // [V, D]
    int T, int D,
    float* __restrict__ partial_b,        // [gridDim.x]
    float* __restrict__ partial_c)        // [gridDim.x]
{
    extern __shared__ char smem[];
    float* se  = (float*)smem;                          // [TILE*ESTRIDE]
    int2*  sic = (int2*)(smem + TILE * ESTRIDE * 4);    // [TILE*D], d-major
    __shared__ float sb[BLOCK / 64];
    __shared__ float sc[BLOCK / 64];

    const int tok0 = blockIdx.x * TILE;
    const int ntok = min(TILE, T - tok0);

    // Stage emb tile into padded LDS (zero-fill past ntok).
    const float4* g4 = (const float4*)(emb + (size_t)tok0 * EMBED);
    for (int j = threadIdx.x; j < TILE * (EMBED / 4); j += BLOCK) {
        const int f = j * 4, tk = f >> 7, kk = f & 127;
        float4 v = make_float4(0.f, 0.f, 0.f, 0.f);
        if (tk < ntok) v = g4[j];
        *(float4*)&se[tk * ESTRIDE + kk] = v;
    }
    // Stage path meta D-MAJOR: sic[d*TILE+tk] = {row, code} or {0,-1}.
    for (int j = threadIdx.x; j < TILE * D; j += BLOCK) {
        const int tk = j & (TILE - 1), d = j >> 6;   // TILE=64
        int2 m = make_int2(0, __float_as_int(-1.0f));
        if (tk < ntok) {
            const int v = target[tok0 + tk];
            const size_t po = (size_t)v * D + d;
            if (path_mask[po] != 0.f)
                m = make_int2(path_idx[po], __float_as_int(path_code[po]));
        }
        sic[j] = m;
    }
    __syncthreads();

    const int wave = threadIdx.x >> 6;          // 0..7
    const int g    = (threadIdx.x >> 2) & 15;   // quad id within wave
    const int sub  = threadIdx.x & 3;           // sub-lane in quad

    float accb = 0.f, accc = 0.f;

    const int items = TILE * D;
    // 8 waves x 16 quads = 128 items per sweep; within a wave-iteration all
    // 16 quads share one depth-slice (same d) -> hot-row L1 broadcast.
    for (int it = wave * 16; it < items; it += 8 * 16) {
        const int item = it + g;                // tk = item&63, d = item>>6
        const int tk   = item & (TILE - 1);
        const int2 m = sic[item];
        const float code = __int_as_float(m.y);
        if (code >= 0.f) {                      // quad-uniform validity
            const float4* w4 = (const float4*)(fc + (size_t)m.x * EMBED);
            const float4* e4 = (const float4*)&se[tk * ESTRIDE];
            float s0 = 0.f, s1 = 0.f, s2 = 0.f, s3 = 0.f;
            #pragma unroll
            for (int k = 0; k < 8; ++k) {
                const float4 w  = w4[k * 4 + sub];
                const float4 ev = e4[k * 4 + sub];
                s0 = fmaf(ev.x, w.x, s0);
                s1 = fmaf(ev.y, w.y, s1);
                s2 = fmaf(ev.z, w.z, s2);
                s3 = fmaf(ev.w, w.w, s3);
            }
            float x = (s0 + s1) + (s2 + s3);
            x += __shfl_xor(x, 1);              // reduce across the quad
            x += __shfl_xor(x, 2);
            accb += fmaxf(x, 0.f) - x * code + __logf(1.f + __expf(-fabsf(x)));
            accc += 1.f;                        // 4x overcount cancels in ratio
        }
    }

    // One reduction per block.
    #pragma unroll
    for (int o = 32; o > 0; o >>= 1) {
        accb += __shfl_xor(accb, o);
        accc += __shfl_xor(accc, o);
    }
    const int lane = threadIdx.x & 63;
    if (lane == 0) { sb[wave] = accb; sc[wave] = accc; }
    __syncthreads();
    if (threadIdx.x == 0) {
        float b = 0.f, c = 0.f;
        #pragma unroll
        for (int i = 0; i < BLOCK / 64; ++i) { b += sb[i]; c += sc[i]; }
        partial_b[blockIdx.x] = b;
        partial_c[blockIdx.x] = c;
    }
}

// Deterministic single-block finalize: double-precision sums, then divide.
__global__ __launch_bounds__(256) void hs_finalize(
    const float* __restrict__ pb,
    const float* __restrict__ pc,
    int n, float* __restrict__ out)
{
    __shared__ double rb[256];
    __shared__ double rc[256];

    double sbv = 0.0, scv = 0.0;
    for (int i = threadIdx.x; i < n; i += 256) {
        sbv += (double)pb[i];
        scv += (double)pc[i];
    }
    rb[threadIdx.x] = sbv;
    rc[threadIdx.x] = scv;
    __syncthreads();

    for (int s = 128; s > 0; s >>= 1) {
        if (threadIdx.x < s) {
            rb[threadIdx.x] += rb[threadIdx.x + s];
            rc[threadIdx.x] += rc[threadIdx.x + s];
        }
        __syncthreads();
    }
    if (threadIdx.x == 0) out[0] = (float)(rb[0] / rc[0]);
}

extern "C" void kernel_launch(void* const* d_in, const int* in_sizes, int n_in,
                              void* d_out, int out_size, void* d_ws, size_t ws_size,
                              hipStream_t stream) {
    const float* emb   = (const float*)d_in[0];
    const int*   tgt   = (const int*)  d_in[1];
    const float* fc    = (const float*)d_in[2];
    const int*   pidx  = (const int*)  d_in[3];
    const float* pcode = (const float*)d_in[4];
    const float* pmask = (const float*)d_in[5];

    const int T = in_sizes[1];            // 32768 tokens
    const int D = in_sizes[3] / VOCAB;    // padded max path depth

    const int nblocks = (T + TILE - 1) / TILE;   // 512
    const size_t shmem = (size_t)TILE * ESTRIDE * 4 + (size_t)TILE * D * 8;

    float* pb = (float*)d_ws;
    float* pc = pb + nblocks;
    float* out = (float*)d_out;

    hs_main<<<nblocks, BLOCK, shmem, stream>>>(
        emb, tgt, fc, pidx, pcode, pmask, T, D, pb, pc);
    hs_finalize<<<1, 256, 0, stream>>>(pb, pc, nblocks, out);
}